// Round 14
// baseline (31342.496 us; speedup 1.0000x reference)
//
#include <hip/hip_runtime.h>
#include <math.h>

// NCA: B=8, H=W=256, C=16, 16 steps. fp32.
// R13 post-mortem: scalar-weight path is architecturally right (VALU stream
// at floor) but 80% stalled: K$ thrash (4 waves x disjoint 16KB), s_load
// latency on shared lgkmcnt with perc ds_reads, only 3 blocks/CU.
// R14: (1) no xs staging -> conv taps from global (L1-hot, 9-neighbor reuse);
// LDS = perc only ~35KB -> 4 blocks/CU (16 waves). (2) perc k-quarter hoisted
// to regs before inner k32 -> hot loop lgkmcnt = s_loads only. (3) dxp
// overlays perc after barrier; epilogue x-center re-read from global.

#define HW 256
#define NPIX (8*HW*HW)   // 524288

// Precompute sobel bank (6 filters, 7x7, normalized).
__global__ void init_kernel(const float* __restrict__ W0,
                            float* __restrict__ filt) {
    int t = blockIdx.x * blockDim.x + threadIdx.x;
    if (t < 6) {
        int f = t;
        int size = 3 + 2*(f >> 1);
        int p0 = (7 - size) >> 1;
        int isY = f & 1;
        float vals[49];
        float norm = 0.f;
        for (int a = 0; a < 7; a++) {
            for (int b = 0; b < 7; b++) {
                float v = 0.f;
                if (a >= p0 && a < p0+size && b >= p0 && b < p0+size) {
                    float fy = (float)(a - 3), fx = (float)(b - 3);
                    float den = fx*fx + fy*fy;
                    if (den == 0.f) den = 1.f;
                    v = (isY ? fy : fx) / den;
                }
                vals[a*7+b] = v;
                norm += fabsf(v);
            }
        }
        float inv = 1.f / norm;
        for (int i = 0; i < 49; i++) filt[f*49 + i] = vals[i] * inv;
    }
}

// One 8x8 pixel tile per block, 256 threads.
// Phase 1: thread=(pixel p=t&63, chan-quad q=t>>6): conv+pool from GLOBAL.
// Phase 2: wave wid owns j [64wid,64wid+64); lane = px; scalar weights.
__launch_bounds__(256, 4)
__global__ void step_main(const float* __restrict__ x,
                          float* __restrict__ xmid,
                          float* __restrict__ alpha_out,
                          float* __restrict__ prelife_out,
                          const float* __restrict__ filt_g,
                          const float* __restrict__ W0,
                          const float* __restrict__ b0,
                          const float* __restrict__ W1,
                          const float* __restrict__ stoch_s) {
    // LDS: perc 64x132 = 8448 fl (dxp [4][64][17]=4352 overlays it after
    // GEMM1 + barrier), filt 294 -> total 8752 fl = 35008 B -> 4 blocks/CU.
    __shared__ float smem[8752];
    float* perc   = smem;            // 64 x 132
    float* dxp    = smem;            // [4][64][17] overlay (post-barrier)
    float* filt_s = smem + 8448;     // 294

    const int t   = threadIdx.x;
    const int b   = blockIdx.z;
    const int ty0 = blockIdx.y * 8;
    const int tx0 = blockIdx.x * 8;

    for (int i = t; i < 294; i += 256) filt_s[i] = filt_g[i];
    __syncthreads();

    {   // ---- phase 1: conv + pools + prelife, taps from global ----
        const int p  = t & 63;
        const int q  = t >> 6;
        const int py = p >> 3, px1 = p & 7;
        const int gy = ty0 + py, gx = tx0 + px1;
        const int q4 = q << 2;
        const float* xb = x + ((((size_t)((b << 8) + gy)) << 8) + gx) * 16 + q4;

        float4 y4[6];
        #pragma unroll
        for (int f = 0; f < 6; f++) y4[f] = make_float4(0.f,0.f,0.f,0.f);
        float4 m5 = make_float4(-INFINITY,-INFINITY,-INFINITY,-INFINITY);
        float pre = -INFINITY;
        float4 xc = make_float4(0.f,0.f,0.f,0.f);

        #pragma unroll
        for (int a = 0; a < 7; a++) {
            #pragma unroll
            for (int bb = 0; bb < 7; bb++) {
                const int dy = a - 3, dxx = bb - 3;
                const bool inb = ((unsigned)(gy+dy) < 256u) && ((unsigned)(gx+dxx) < 256u);
                float4 xv = make_float4(0.f,0.f,0.f,0.f);
                if (inb)
                    xv = *(const float4*)(xb + ((dy << 8) + dxx) * 16);
                #pragma unroll
                for (int f = 0; f < 6; f++) {
                    float w = filt_s[f*49 + a*7 + bb];
                    y4[f].x = fmaf(w, xv.x, y4[f].x);
                    y4[f].y = fmaf(w, xv.y, y4[f].y);
                    y4[f].z = fmaf(w, xv.z, y4[f].z);
                    y4[f].w = fmaf(w, xv.w, y4[f].w);
                }
                if (inb && dy >= -2 && dy <= 2 && dxx >= -2 && dxx <= 2) {
                    m5.x = fmaxf(m5.x, xv.x); m5.y = fmaxf(m5.y, xv.y);
                    m5.z = fmaxf(m5.z, xv.z); m5.w = fmaxf(m5.w, xv.w);
                }
                if (q == 0 && inb && dy >= -1 && dy <= 1 && dxx >= -1 && dxx <= 1)
                    pre = fmaxf(pre, xv.w);   // channel 3 = .w of quad 0
                if (dy == 0 && dxx == 0) xc = xv;
            }
        }
        // perc: [0:16)=x, [16+f*16+c)=y (f-major), [112:128)=pool5
        *(float4*)&perc[p*132 + q4] = xc;
        #pragma unroll
        for (int f = 0; f < 6; f++)
            *(float4*)&perc[p*132 + 16 + f*16 + q4] = y4[f];
        *(float4*)&perc[p*132 + 112 + q4] = m5;

        if (q == 0)
            prelife_out[(b << 16) + (gy << 8) + gx] = (pre > 0.1f) ? 1.f : 0.f;
    }
    __syncthreads();   // perc visible to all waves

    // ---- phase 2: MLP. wave wid owns j [64wid,64wid+64); lane = px ----
    const int wid = __builtin_amdgcn_readfirstlane(t >> 6);
    const int px  = t & 63;
    const float* percP = &perc[px * 132];

    float dx[16];
    #pragma unroll
    for (int c = 0; c < 16; c++) dx[c] = 0.f;

    #pragma unroll 1
    for (int pass = 0; pass < 2; pass++) {
        const int jbase = (wid << 6) + (pass << 5);   // uniform
        float h[32];
        #pragma unroll
        for (int jj = 0; jj < 32; jj++) h[jj] = 0.f;

        #pragma unroll 1
        for (int kq = 0; kq < 4; kq++) {
            // hoist perc k-quarter into registers: hot loop is s_load-only
            float4 pv[8];
            #pragma unroll
            for (int r = 0; r < 8; r++)
                pv[r] = *(const float4*)&percP[(kq << 5) + (r << 2)];
            const float* w0k = W0 + ((kq << 5) << 8) + jbase;   // uniform

            #pragma unroll
            for (int r = 0; r < 8; r++) {
                #pragma unroll
                for (int kk = 0; kk < 4; kk++) {
                    float a = kk==0?pv[r].x : kk==1?pv[r].y : kk==2?pv[r].z : pv[r].w;
                    const float4* wr = (const float4*)(w0k + (((r << 2) + kk) << 8));
                    float4 w0v = wr[0], w1v = wr[1], w2v = wr[2], w3v = wr[3];
                    float4 w4v = wr[4], w5v = wr[5], w6v = wr[6], w7v = wr[7];
                    h[0]  = fmaf(a, w0v.x, h[0]);  h[1]  = fmaf(a, w0v.y, h[1]);
                    h[2]  = fmaf(a, w0v.z, h[2]);  h[3]  = fmaf(a, w0v.w, h[3]);
                    h[4]  = fmaf(a, w1v.x, h[4]);  h[5]  = fmaf(a, w1v.y, h[5]);
                    h[6]  = fmaf(a, w1v.z, h[6]);  h[7]  = fmaf(a, w1v.w, h[7]);
                    h[8]  = fmaf(a, w2v.x, h[8]);  h[9]  = fmaf(a, w2v.y, h[9]);
                    h[10] = fmaf(a, w2v.z, h[10]); h[11] = fmaf(a, w2v.w, h[11]);
                    h[12] = fmaf(a, w3v.x, h[12]); h[13] = fmaf(a, w3v.y, h[13]);
                    h[14] = fmaf(a, w3v.z, h[14]); h[15] = fmaf(a, w3v.w, h[15]);
                    h[16] = fmaf(a, w4v.x, h[16]); h[17] = fmaf(a, w4v.y, h[17]);
                    h[18] = fmaf(a, w4v.z, h[18]); h[19] = fmaf(a, w4v.w, h[19]);
                    h[20] = fmaf(a, w5v.x, h[20]); h[21] = fmaf(a, w5v.y, h[21]);
                    h[22] = fmaf(a, w5v.z, h[22]); h[23] = fmaf(a, w5v.w, h[23]);
                    h[24] = fmaf(a, w6v.x, h[24]); h[25] = fmaf(a, w6v.y, h[25]);
                    h[26] = fmaf(a, w6v.z, h[26]); h[27] = fmaf(a, w6v.w, h[27]);
                    h[28] = fmaf(a, w7v.x, h[28]); h[29] = fmaf(a, w7v.y, h[29]);
                    h[30] = fmaf(a, w7v.z, h[30]); h[31] = fmaf(a, w7v.w, h[31]);
                }
            }
        }
        // bias + relu (uniform)
        {
            const float4* bv = (const float4*)(b0 + jbase);
            float4 b0v = bv[0], b1v = bv[1], b2v = bv[2], b3v = bv[3];
            float4 b4v = bv[4], b5v = bv[5], b6v = bv[6], b7v = bv[7];
            h[0]  = fmaxf(h[0]  + b0v.x, 0.f); h[1]  = fmaxf(h[1]  + b0v.y, 0.f);
            h[2]  = fmaxf(h[2]  + b0v.z, 0.f); h[3]  = fmaxf(h[3]  + b0v.w, 0.f);
            h[4]  = fmaxf(h[4]  + b1v.x, 0.f); h[5]  = fmaxf(h[5]  + b1v.y, 0.f);
            h[6]  = fmaxf(h[6]  + b1v.z, 0.f); h[7]  = fmaxf(h[7]  + b1v.w, 0.f);
            h[8]  = fmaxf(h[8]  + b2v.x, 0.f); h[9]  = fmaxf(h[9]  + b2v.y, 0.f);
            h[10] = fmaxf(h[10] + b2v.z, 0.f); h[11] = fmaxf(h[11] + b2v.w, 0.f);
            h[12] = fmaxf(h[12] + b3v.x, 0.f); h[13] = fmaxf(h[13] + b3v.y, 0.f);
            h[14] = fmaxf(h[14] + b3v.z, 0.f); h[15] = fmaxf(h[15] + b3v.w, 0.f);
            h[16] = fmaxf(h[16] + b4v.x, 0.f); h[17] = fmaxf(h[17] + b4v.y, 0.f);
            h[18] = fmaxf(h[18] + b4v.z, 0.f); h[19] = fmaxf(h[19] + b4v.w, 0.f);
            h[20] = fmaxf(h[20] + b5v.x, 0.f); h[21] = fmaxf(h[21] + b5v.y, 0.f);
            h[22] = fmaxf(h[22] + b5v.z, 0.f); h[23] = fmaxf(h[23] + b5v.w, 0.f);
            h[24] = fmaxf(h[24] + b6v.x, 0.f); h[25] = fmaxf(h[25] + b6v.y, 0.f);
            h[26] = fmaxf(h[26] + b6v.z, 0.f); h[27] = fmaxf(h[27] + b6v.w, 0.f);
            h[28] = fmaxf(h[28] + b7v.x, 0.f); h[29] = fmaxf(h[29] + b7v.y, 0.f);
            h[30] = fmaxf(h[30] + b7v.z, 0.f); h[31] = fmaxf(h[31] + b7v.w, 0.f);
        }
        // GEMM2 (uniform W1)
        #pragma unroll
        for (int jj = 0; jj < 32; jj++) {
            const float4* w1r = (const float4*)(W1 + ((jbase + jj) << 4));
            float4 wa = w1r[0], wb = w1r[1], wc = w1r[2], wd = w1r[3];
            float hv = h[jj];
            dx[0]  = fmaf(hv, wa.x, dx[0]);  dx[1]  = fmaf(hv, wa.y, dx[1]);
            dx[2]  = fmaf(hv, wa.z, dx[2]);  dx[3]  = fmaf(hv, wa.w, dx[3]);
            dx[4]  = fmaf(hv, wb.x, dx[4]);  dx[5]  = fmaf(hv, wb.y, dx[5]);
            dx[6]  = fmaf(hv, wb.z, dx[6]);  dx[7]  = fmaf(hv, wb.w, dx[7]);
            dx[8]  = fmaf(hv, wc.x, dx[8]);  dx[9]  = fmaf(hv, wc.y, dx[9]);
            dx[10] = fmaf(hv, wc.z, dx[10]); dx[11] = fmaf(hv, wc.w, dx[11]);
            dx[12] = fmaf(hv, wd.x, dx[12]); dx[13] = fmaf(hv, wd.y, dx[13]);
            dx[14] = fmaf(hv, wd.z, dx[14]); dx[15] = fmaf(hv, wd.w, dx[15]);
        }
    }

    __syncthreads();   // ALL waves done reading perc before dxp overlay
    {
        float* dpw = &dxp[((wid << 6) + px) * 17];
        #pragma unroll
        for (int c = 0; c < 16; c++) dpw[c] = dx[c];
    }
    __syncthreads();

    // epilogue: thread = (pixel ep=t>>2, chan-quad cq=t&3)
    const int ep = t >> 2;
    const int cq = t & 3;
    const int co = cq << 2;
    float s0 = 0.f, s1 = 0.f, s2 = 0.f, s3 = 0.f;
    #pragma unroll
    for (int w = 0; w < 4; w++) {
        const float* dpr = &dxp[((w << 6) + ep) * 17 + co];
        s0 += dpr[0]; s1 += dpr[1]; s2 += dpr[2]; s3 += dpr[3];
    }
    const int ppy = ep >> 3, ppx = ep & 7;
    const int pix2 = (b << 16) + ((ty0 + ppy) << 8) + (tx0 + ppx);
    float fire = (stoch_s[pix2] > 0.5f) ? 1.f : 0.f;
    float4 xc2 = *(const float4*)&x[(((size_t)pix2) << 4) + co];   // L2-hot
    float4 xn;
    xn.x = fmaf(fire, s0, xc2.x);
    xn.y = fmaf(fire, s1, xc2.y);
    xn.z = fmaf(fire, s2, xc2.z);
    xn.w = fmaf(fire, s3, xc2.w);
    *(float4*)&xmid[(((size_t)pix2) << 4) + co] = xn;
    if (cq == 0) alpha_out[pix2] = xn.w;   // channel 3
}

// In-place life masking: reads alpha_new from the separate plane (race-free).
__global__ void step_mask(float* __restrict__ xbuf,
                          const float* __restrict__ alpha,
                          const float* __restrict__ prelife,
                          const float* __restrict__ valid) {
    int pix = blockIdx.x * 256 + threadIdx.x;
    int b = pix >> 16;
    int y = (pix >> 8) & 255;
    int x = pix & 255;
    float m = -INFINITY;
    #pragma unroll
    for (int dy = -1; dy <= 1; dy++) {
        #pragma unroll
        for (int dxo = -1; dxo <= 1; dxo++) {
            int yy = y + dy, xx = x + dxo;
            if ((unsigned)yy < 256u && (unsigned)xx < 256u)
                m = fmaxf(m, alpha[(b << 16) + (yy << 8) + xx]);
        }
    }
    float life = (prelife[pix] != 0.f && m > 0.1f) ? 1.f : 0.f;
    float s = life * valid[pix];
    float4* xp = (float4*)&xbuf[(size_t)pix << 4];
    #pragma unroll
    for (int i = 0; i < 4; i++) {
        float4 v = xp[i];
        v.x *= s; v.y *= s; v.z *= s; v.w *= s;
        xp[i] = v;
    }
}

extern "C" void kernel_launch(void* const* d_in, const int* in_sizes, int n_in,
                              void* d_out, int out_size, void* d_ws, size_t ws_size,
                              hipStream_t stream) {
    const float* x0    = (const float*)d_in[0];
    const float* valid = (const float*)d_in[1];
    const float* stoch = (const float*)d_in[2];
    const float* W0    = (const float*)d_in[3];
    const float* b0    = (const float*)d_in[4];
    const float* W1    = (const float*)d_in[5];

    float* ws      = (float*)d_ws;
    float* xA      = ws;                 // 8388608 floats
    float* alpha   = ws + 8388608;       // 524288
    float* prelife = ws + 8912896;       // 524288
    float* filt    = ws + 9437184;       // 294 (+pad)
    float* out     = (float*)d_out;

    init_kernel<<<1, 64, 0, stream>>>(W0, filt);

    const float* src = x0;
    for (int k = 1; k <= 16; k++) {
        float* dst = (k & 1) ? xA : out;   // step 16 (even) lands in d_out
        step_main<<<dim3(32,32,8), 256, 0, stream>>>(
            src, dst, alpha, prelife, filt, W0, b0, W1,
            stoch + (size_t)(k-1)*NPIX);
        step_mask<<<NPIX/256, 256, 0, stream>>>(dst, alpha, prelife, valid);
        src = dst;
    }
}

// Round 15
// 15389.980 us; speedup vs baseline: 2.0366x; 2.0366x over previous
//
#include <hip/hip_runtime.h>
#include <math.h>

// NCA: B=8, H=W=256, C=16, 16 steps. fp32.
// R14 post-mortem: launch_bounds(256,4) -> 64-VGPR cap -> spill again (R5's
// failure from the occupancy side). Best = R12 structure (step ~1.5ms,
// VALU+LDS co-saturated at 2 blocks/CU).
// R15 = R12 + (1) double-buffered w0s: ONE barrier per chunk (9 vs 17);
// LDS 72.7KB, still 2 blocks/CU. (2) sparse conv: sobel 3x3/5x5 filters only
// multiplied inside their support (664 vs 1176 FMA/thread).

#define HW 256
#define NPIX (8*HW*HW)   // 524288
#define PST 140          // perc row stride (floats)

__device__ __forceinline__ float4 f4max(float4 a, float4 b) {
    return make_float4(fmaxf(a.x,b.x), fmaxf(a.y,b.y), fmaxf(a.z,b.z), fmaxf(a.w,b.w));
}

// Precompute sobel bank (6 filters, 7x7, normalized).
__global__ void init_kernel(const float* __restrict__ W0,
                            float* __restrict__ filt) {
    int t = blockIdx.x * blockDim.x + threadIdx.x;
    if (t < 6) {
        int f = t;
        int size = 3 + 2*(f >> 1);
        int p0 = (7 - size) >> 1;
        int isY = f & 1;
        float vals[49];
        float norm = 0.f;
        for (int a = 0; a < 7; a++) {
            for (int b = 0; b < 7; b++) {
                float v = 0.f;
                if (a >= p0 && a < p0+size && b >= p0 && b < p0+size) {
                    float fy = (float)(a - 3), fx = (float)(b - 3);
                    float den = fx*fx + fy*fy;
                    if (den == 0.f) den = 1.f;
                    v = (isY ? fy : fx) / den;
                }
                vals[a*7+b] = v;
                norm += fabsf(v);
            }
        }
        float inv = 1.f / norm;
        for (int i = 0; i < 49; i++) filt[f*49 + i] = vals[i] * inv;
    }
}

// One 8x8 pixel tile per block, 256 threads.
__launch_bounds__(256, 2)
__global__ void step_main(const float* __restrict__ x,
                          float* __restrict__ xmid,
                          float* __restrict__ alpha_out,
                          float* __restrict__ prelife_out,
                          const float* __restrict__ filt_g,
                          const float* __restrict__ W0,
                          const float* __restrict__ b0,
                          const float* __restrict__ W1,
                          const float* __restrict__ stoch_s) {
    // carve: phase1 xs [0,3920) + filt [3920,4214)
    //        phase2 w0sA [0,4608) | w0sB [4608,9216)
    //        perc [9216,18176)   -> 72704 B, 2 blocks/CU
    __shared__ float smem[18176];
    float* xs     = smem;          // 14*14*20 = 3920 (phase 1 only)
    float* filt_s = smem + 3920;   // 294 (phase 1 only)
    float* w0sA   = smem;          // 128x36 (phase 2)
    float* w0sB   = smem + 4608;   // 128x36 (phase 2)
    float* perc   = smem + 9216;   // 64 x 140

    const int t   = threadIdx.x;
    const int b   = blockIdx.z;
    const int ty0 = blockIdx.y * 8;
    const int tx0 = blockIdx.x * 8;

    // T14 prologue: issue chunk-0 W0 loads NOW; they land during phase 1.
    const float* pW   = W0 + ((t >> 3) << 8) + ((t & 7) << 2);
    const int   wbase = (t >> 3) * 144 + ((t & 7) << 2);
    float4 st0 = *(const float4*)(pW);
    float4 st1 = *(const float4*)(pW +  8192);
    float4 st2 = *(const float4*)(pW + 16384);
    float4 st3 = *(const float4*)(pW + 24576);

    for (int i = t; i < 294; i += 256) filt_s[i] = filt_g[i];

    // stage x tile + halo (zero pad = conv's zero padding)
    for (int v = t; v < 784; v += 256) {          // 14*14*4 float4s
        int c4  = v & 3;
        int cell = v >> 2;
        int ly = cell / 14;
        int lx = cell - ly*14;
        int gy = ty0 + ly - 3, gx = tx0 + lx - 3;
        float4 val = make_float4(0.f,0.f,0.f,0.f);
        if ((unsigned)gy < 256u && (unsigned)gx < 256u)
            val = *(const float4*)&x[((((b<<8) + gy)<<8) + gx)*16 + (c4<<2)];
        *(float4*)&xs[cell*20 + (c4<<2)] = val;
    }
    __syncthreads();

    {   // ---- phase 1: sparse conv + pools -> perc ----
        const int p  = t & 63;
        const int q  = t >> 6;
        const int py = p >> 3, px1 = p & 7;
        const int gy = ty0 + py, gx = tx0 + px1;
        const int q4 = q << 2;

        float4 y4[6];
        #pragma unroll
        for (int f = 0; f < 6; f++) y4[f] = make_float4(0.f,0.f,0.f,0.f);

        #pragma unroll
        for (int a = 0; a < 7; a++) {
            #pragma unroll
            for (int bb = 0; bb < 7; bb++) {
                float4 xv = *(const float4*)&xs[((py+a)*14 + (px1+bb))*20 + q4];
                {   // f=4,5: full 7x7
                    float w4 = filt_s[4*49 + a*7 + bb];
                    float w5 = filt_s[5*49 + a*7 + bb];
                    y4[4].x = fmaf(w4, xv.x, y4[4].x); y4[4].y = fmaf(w4, xv.y, y4[4].y);
                    y4[4].z = fmaf(w4, xv.z, y4[4].z); y4[4].w = fmaf(w4, xv.w, y4[4].w);
                    y4[5].x = fmaf(w5, xv.x, y4[5].x); y4[5].y = fmaf(w5, xv.y, y4[5].y);
                    y4[5].z = fmaf(w5, xv.z, y4[5].z); y4[5].w = fmaf(w5, xv.w, y4[5].w);
                }
                if (a >= 1 && a <= 5 && bb >= 1 && bb <= 5) {   // f=2,3: 5x5
                    float w2 = filt_s[2*49 + a*7 + bb];
                    float w3 = filt_s[3*49 + a*7 + bb];
                    y4[2].x = fmaf(w2, xv.x, y4[2].x); y4[2].y = fmaf(w2, xv.y, y4[2].y);
                    y4[2].z = fmaf(w2, xv.z, y4[2].z); y4[2].w = fmaf(w2, xv.w, y4[2].w);
                    y4[3].x = fmaf(w3, xv.x, y4[3].x); y4[3].y = fmaf(w3, xv.y, y4[3].y);
                    y4[3].z = fmaf(w3, xv.z, y4[3].z); y4[3].w = fmaf(w3, xv.w, y4[3].w);
                }
                if (a >= 2 && a <= 4 && bb >= 2 && bb <= 4) {   // f=0,1: 3x3
                    float w0 = filt_s[0*49 + a*7 + bb];
                    float w1 = filt_s[1*49 + a*7 + bb];
                    y4[0].x = fmaf(w0, xv.x, y4[0].x); y4[0].y = fmaf(w0, xv.y, y4[0].y);
                    y4[0].z = fmaf(w0, xv.z, y4[0].z); y4[0].w = fmaf(w0, xv.w, y4[0].w);
                    y4[1].x = fmaf(w1, xv.x, y4[1].x); y4[1].y = fmaf(w1, xv.y, y4[1].y);
                    y4[1].z = fmaf(w1, xv.z, y4[1].z); y4[1].w = fmaf(w1, xv.w, y4[1].w);
                }
            }
        }
        float4 m5 = make_float4(-INFINITY,-INFINITY,-INFINITY,-INFINITY);
        #pragma unroll
        for (int dy = -2; dy <= 2; dy++) {
            #pragma unroll
            for (int dx2 = -2; dx2 <= 2; dx2++) {
                if ((unsigned)(gy+dy) < 256u && (unsigned)(gx+dx2) < 256u)
                    m5 = f4max(m5, *(const float4*)&xs[((py+3+dy)*14 + (px1+3+dx2))*20 + q4]);
            }
        }
        // perc channel c stored at (c>>5)*36 + (c&31)
        float4 xc = *(const float4*)&xs[((py+3)*14 + (px1+3))*20 + q4];
        *(float4*)&perc[p*PST + q4] = xc;
        const int offY[6] = {16, 36, 52, 72, 88, 108};
        #pragma unroll
        for (int f = 0; f < 6; f++)
            *(float4*)&perc[p*PST + offY[f] + q4] = y4[f];
        *(float4*)&perc[p*PST + 124 + q4] = m5;

        if (q == 0) {
            float pre = -INFINITY;
            #pragma unroll
            for (int dy = -1; dy <= 1; dy++) {
                #pragma unroll
                for (int dx2 = -1; dx2 <= 1; dx2++) {
                    if ((unsigned)(gy+dy) < 256u && (unsigned)(gx+dx2) < 256u)
                        pre = fmaxf(pre, xs[((py+3+dy)*14 + (px1+3+dx2))*20 + 3]);
                }
            }
            prelife_out[(b << 16) + (gy << 8) + gx] = (pre > 0.1f) ? 1.f : 0.f;
        }
    }
    __syncthreads();   // xs reads done; perc published. xs region -> w0sA.

    // ---- phase 2: MLP, double-buffered w0s ----
    const int kq   = t & 3;
    const int jg   = (t >> 2) & 3;
    const int quad = t >> 4;        // owns 4 consecutive px {4quad..4quad+3}
    const int jg8  = jg << 3;
    const int p0px = quad << 2;

    const float* pp0 = &perc[(p0px    ) * PST + kq*36];
    const float* pp1 = &perc[(p0px + 1) * PST + kq*36];
    const float* pp2 = &perc[(p0px + 2) * PST + kq*36];
    const float* pp3 = &perc[(p0px + 3) * PST + kq*36];

    float dx[4][4];
    #pragma unroll
    for (int i = 0; i < 4; i++)
        #pragma unroll
        for (int c = 0; c < 4; c++) dx[i][c] = 0.f;

    // prologue: write chunk 0 -> A; issue chunk-1 loads
    *(float4*)&w0sA[wbase      ] = st0;
    *(float4*)&w0sA[wbase +  36] = st1;
    *(float4*)&w0sA[wbase +  72] = st2;
    *(float4*)&w0sA[wbase + 108] = st3;
    st0 = *(const float4*)(pW + 32);
    st1 = *(const float4*)(pW + 32 +  8192);
    st2 = *(const float4*)(pW + 32 + 16384);
    st3 = *(const float4*)(pW + 32 + 24576);
    __syncthreads();   // A visible

    #pragma unroll 1
    for (int jc = 0; jc < 8; jc++) {
        const float* wrd = (jc & 1) ? w0sB : w0sA;   // chunk jc
        float*       wwr = (jc & 1) ? w0sA : w0sB;   // chunk jc+1

        float h[4][8];
        #pragma unroll
        for (int i = 0; i < 4; i++)
            #pragma unroll
            for (int jj = 0; jj < 8; jj++) h[i][jj] = 0.f;

        #pragma unroll
        for (int k4 = 0; k4 < 32; k4 += 4) {
            float4 pA0 = *(const float4*)&pp0[k4];
            float4 pA1 = *(const float4*)&pp1[k4];
            float4 pA2 = *(const float4*)&pp2[k4];
            float4 pA3 = *(const float4*)&pp3[k4];
            #pragma unroll
            for (int kk = 0; kk < 4; kk++) {
                float a0 = kk==0?pA0.x : kk==1?pA0.y : kk==2?pA0.z : pA0.w;
                float a1 = kk==0?pA1.x : kk==1?pA1.y : kk==2?pA1.z : pA1.w;
                float a2 = kk==0?pA2.x : kk==1?pA2.y : kk==2?pA2.z : pA2.w;
                float a3 = kk==0?pA3.x : kk==1?pA3.y : kk==2?pA3.z : pA3.w;
                const float* wr = &wrd[((k4 + kk)*4 + kq)*36 + jg8];
                float4 wA = *(const float4*)wr;
                float4 wB = *(const float4*)(wr + 4);
                #pragma unroll
                for (int i = 0; i < 4; i++) {
                    float ai = i==0?a0 : i==1?a1 : i==2?a2 : a3;
                    h[i][0] = fmaf(ai, wA.x, h[i][0]);
                    h[i][1] = fmaf(ai, wA.y, h[i][1]);
                    h[i][2] = fmaf(ai, wA.z, h[i][2]);
                    h[i][3] = fmaf(ai, wA.w, h[i][3]);
                    h[i][4] = fmaf(ai, wB.x, h[i][4]);
                    h[i][5] = fmaf(ai, wB.y, h[i][5]);
                    h[i][6] = fmaf(ai, wB.z, h[i][6]);
                    h[i][7] = fmaf(ai, wB.w, h[i][7]);
                }
            }
        }
        // reduce h over the 4 kq lanes (bits 0-1)
        #pragma unroll
        for (int i = 0; i < 4; i++)
            #pragma unroll
            for (int jj = 0; jj < 8; jj++) {
                h[i][jj] += __shfl_xor(h[i][jj], 1);
                h[i][jj] += __shfl_xor(h[i][jj], 2);
            }
        // bias + relu
        const int jbase = (jc << 5) + jg8;
        float4 bA = *(const float4*)&b0[jbase];
        float4 bB = *(const float4*)&b0[jbase + 4];
        #pragma unroll
        for (int i = 0; i < 4; i++) {
            h[i][0] = fmaxf(h[i][0] + bA.x, 0.f);
            h[i][1] = fmaxf(h[i][1] + bA.y, 0.f);
            h[i][2] = fmaxf(h[i][2] + bA.z, 0.f);
            h[i][3] = fmaxf(h[i][3] + bA.w, 0.f);
            h[i][4] = fmaxf(h[i][4] + bB.x, 0.f);
            h[i][5] = fmaxf(h[i][5] + bB.y, 0.f);
            h[i][6] = fmaxf(h[i][6] + bB.z, 0.f);
            h[i][7] = fmaxf(h[i][7] + bB.w, 0.f);
        }
        // GEMM2: this lane's channel-quad kq*4..+4
        #pragma unroll
        for (int jj = 0; jj < 8; jj++) {
            float4 wv = *(const float4*)&W1[((jbase + jj) << 4) + (kq << 2)];
            #pragma unroll
            for (int i = 0; i < 4; i++) {
                dx[i][0] = fmaf(h[i][jj], wv.x, dx[i][0]);
                dx[i][1] = fmaf(h[i][jj], wv.y, dx[i][1]);
                dx[i][2] = fmaf(h[i][jj], wv.z, dx[i][2]);
                dx[i][3] = fmaf(h[i][jj], wv.w, dx[i][3]);
            }
        }

        // stage chunk jc+1 into the other buffer; issue chunk jc+2 loads
        if (jc < 7) {
            *(float4*)&wwr[wbase      ] = st0;
            *(float4*)&wwr[wbase +  36] = st1;
            *(float4*)&wwr[wbase +  72] = st2;
            *(float4*)&wwr[wbase + 108] = st3;
            if (jc < 6) {
                const float* pN = pW + ((jc + 2) << 5);
                st0 = *(const float4*)(pN);
                st1 = *(const float4*)(pN +  8192);
                st2 = *(const float4*)(pN + 16384);
                st3 = *(const float4*)(pN + 24576);
            }
            __syncthreads();   // single barrier per chunk
        }
    }

    // reduce dx over the 4 jg lanes (bits 2-3)
    #pragma unroll
    for (int i = 0; i < 4; i++)
        #pragma unroll
        for (int c = 0; c < 4; c++) {
            dx[i][c] += __shfl_xor(dx[i][c], 4);
            dx[i][c] += __shfl_xor(dx[i][c], 8);
        }

    // writer: pixel 4quad+jg, channels kq*4..+4
    float o0 = jg==0?dx[0][0] : jg==1?dx[1][0] : jg==2?dx[2][0] : dx[3][0];
    float o1 = jg==0?dx[0][1] : jg==1?dx[1][1] : jg==2?dx[2][1] : dx[3][1];
    float o2 = jg==0?dx[0][2] : jg==1?dx[1][2] : jg==2?dx[2][2] : dx[3][2];
    float o3 = jg==0?dx[0][3] : jg==1?dx[1][3] : jg==2?dx[2][3] : dx[3][3];

    const int pw  = p0px + jg;
    const int ppy = pw >> 3, ppx = pw & 7;
    const int pix2 = (b << 16) + ((ty0 + ppy) << 8) + (tx0 + ppx);
    float fire = (stoch_s[pix2] > 0.5f) ? 1.f : 0.f;
    float4 xc2 = *(const float4*)&perc[pw*PST + (kq << 2)];
    float4 xn;
    xn.x = fmaf(fire, o0, xc2.x);
    xn.y = fmaf(fire, o1, xc2.y);
    xn.z = fmaf(fire, o2, xc2.z);
    xn.w = fmaf(fire, o3, xc2.w);
    *(float4*)&xmid[((size_t)pix2 << 4) + (kq << 2)] = xn;
    if (kq == 0) alpha_out[pix2] = xn.w;   // channel 3
}

// In-place life masking: reads alpha_new from the separate plane (race-free).
__global__ void step_mask(float* __restrict__ xbuf,
                          const float* __restrict__ alpha,
                          const float* __restrict__ prelife,
                          const float* __restrict__ valid) {
    int pix = blockIdx.x * 256 + threadIdx.x;
    int b = pix >> 16;
    int y = (pix >> 8) & 255;
    int x = pix & 255;
    float m = -INFINITY;
    #pragma unroll
    for (int dy = -1; dy <= 1; dy++) {
        #pragma unroll
        for (int dxo = -1; dxo <= 1; dxo++) {
            int yy = y + dy, xx = x + dxo;
            if ((unsigned)yy < 256u && (unsigned)xx < 256u)
                m = fmaxf(m, alpha[(b << 16) + (yy << 8) + xx]);
        }
    }
    float life = (prelife[pix] != 0.f && m > 0.1f) ? 1.f : 0.f;
    float s = life * valid[pix];
    float4* xp = (float4*)&xbuf[(size_t)pix << 4];
    #pragma unroll
    for (int i = 0; i < 4; i++) {
        float4 v = xp[i];
        v.x *= s; v.y *= s; v.z *= s; v.w *= s;
        xp[i] = v;
    }
}

extern "C" void kernel_launch(void* const* d_in, const int* in_sizes, int n_in,
                              void* d_out, int out_size, void* d_ws, size_t ws_size,
                              hipStream_t stream) {
    const float* x0    = (const float*)d_in[0];
    const float* valid = (const float*)d_in[1];
    const float* stoch = (const float*)d_in[2];
    const float* W0    = (const float*)d_in[3];
    const float* b0    = (const float*)d_in[4];
    const float* W1    = (const float*)d_in[5];

    float* ws      = (float*)d_ws;
    float* xA      = ws;                 // 8388608 floats
    float* alpha   = ws + 8388608;       // 524288
    float* prelife = ws + 8912896;       // 524288
    float* filt    = ws + 9437184;       // 294 (+pad)
    float* out     = (float*)d_out;

    init_kernel<<<1, 64, 0, stream>>>(W0, filt);

    const float* src = x0;
    for (int k = 1; k <= 16; k++) {
        float* dst = (k & 1) ? xA : out;   // step 16 (even) lands in d_out
        step_main<<<dim3(32,32,8), 256, 0, stream>>>(
            src, dst, alpha, prelife, filt, W0, b0, W1,
            stoch + (size_t)(k-1)*NPIX);
        step_mask<<<NPIX/256, 256, 0, stream>>>(dst, alpha, prelife, valid);
        src = dst;
    }
}